// Round 1
// baseline (23.620 us; speedup 1.0000x reference)
//
#include <hip/hip_runtime.h>

#define N_SAMP 8192
#define NT     1024
#define PER_T  (N_SAMP / NT)   // 8 samples per thread

__global__ __launch_bounds__(NT) void ranknet_kernel(
    const float* __restrict__ scores,   // [N_DOCS, 1]
    const int*   __restrict__ target,   // [N_DOCS]
    const int*   __restrict__ docs,     // [N_SAMP]
    float*       __restrict__ out)      // [1]
{
    __shared__ int    s_cnt[5];
    __shared__ float  s_scan[NT];
    __shared__ double s_red[NT / 64];

    const int tid = threadIdx.x;
    if (tid < 5) s_cnt[tid] = 0;
    __syncthreads();

    // ---- gather sampled targets/scores; build local histogram ----
    int   t[PER_T];
    float sc[PER_T];
    int   lc[5] = {0, 0, 0, 0, 0};
    #pragma unroll
    for (int e = 0; e < PER_T; ++e) {
        const int k = tid * PER_T + e;   // contiguous chunk per thread (scan order)
        const int d = docs[k];
        const int tv = target[d];
        t[e]  = tv;
        sc[e] = scores[d];
        ++lc[tv];
    }

    // wave-level reduce of histogram, one LDS atomic per wave per bin
    #pragma unroll
    for (int v = 0; v < 5; ++v) {
        int c = lc[v];
        #pragma unroll
        for (int off = 32; off > 0; off >>= 1)
            c += __shfl_down(c, off, 64);
        if ((tid & 63) == 0) atomicAdd(&s_cnt[v], c);
    }
    __syncthreads();

    // ---- R[v] = 0.5 * (greater(v) - less(v)) from the histogram ----
    float R[5];
    {
        int cnt[5], total = 0;
        #pragma unroll
        for (int v = 0; v < 5; ++v) { cnt[v] = s_cnt[v]; total += cnt[v]; }
        int less = 0;
        #pragma unroll
        for (int v = 0; v < 5; ++v) {
            const int greater = total - less - cnt[v];
            R[v] = 0.5f * (float)(greater - less);
            less += cnt[v];
        }
    }

    // ---- local rows + local inclusive prefix ----
    float rowsum = 0.0f;
    float localpref[PER_T];
    #pragma unroll
    for (int e = 0; e < PER_T; ++e) {
        rowsum += R[t[e]];
        localpref[e] = rowsum;
    }

    // ---- block-wide inclusive scan (Hillis–Steele) of per-thread sums ----
    s_scan[tid] = rowsum;
    __syncthreads();
    for (int off = 1; off < NT; off <<= 1) {
        const float v = (tid >= off) ? s_scan[tid - off] : 0.0f;
        __syncthreads();
        s_scan[tid] += v;
        __syncthreads();
    }
    const float excl = (tid == 0) ? 0.0f : s_scan[tid - 1];

    // ---- loss partial: sum_k cum_k * s_k (double accumulate) ----
    double part = 0.0;
    #pragma unroll
    for (int e = 0; e < PER_T; ++e) {
        const float cum = excl + localpref[e];
        part += (double)cum * (double)sc[e];
    }
    #pragma unroll
    for (int off = 32; off > 0; off >>= 1)
        part += __shfl_down(part, off, 64);
    if ((tid & 63) == 0) s_red[tid >> 6] = part;
    __syncthreads();

    if (tid == 0) {
        double tot = 0.0;
        #pragma unroll
        for (int w = 0; w < NT / 64; ++w) tot += s_red[w];
        out[0] = (float)tot;
    }
}

extern "C" void kernel_launch(void* const* d_in, const int* in_sizes, int n_in,
                              void* d_out, int out_size, void* d_ws, size_t ws_size,
                              hipStream_t stream) {
    const float* scores = (const float*)d_in[0];
    const int*   target = (const int*)d_in[1];
    const int*   docs   = (const int*)d_in[2];
    float*       out    = (float*)d_out;

    ranknet_kernel<<<1, NT, 0, stream>>>(scores, target, docs, out);
}

// Round 2
// 11.786 us; speedup vs baseline: 2.0041x; 2.0041x over previous
//
#include <hip/hip_runtime.h>

#define NS  8192
#define B1  64      // gather blocks
#define T1  128     // threads per gather block (B1*T1 == NS)
#define REC 12      // floats per block record in ws: cnt[5], Pq[5], ssum, pad

// Kernel 1: per-block gather + local stats.
// For block b over samples m in [b*T1, (b+1)*T1):
//   cnt[v]  = #{m in b : t_m == v}
//   Pq[v]   = sum_{m in b, t_m == v} (exclusive prefix of s within block)
//   ssum    = sum of s over block
__global__ __launch_bounds__(T1) void k_gather(
    const float* __restrict__ scores,   // [N_DOCS, 1]
    const int*   __restrict__ target,   // [N_DOCS]
    const int*   __restrict__ docs,     // [NS]
    float*       __restrict__ ws)       // [B1 * REC]
{
    const int tid  = threadIdx.x;
    const int b    = blockIdx.x;
    const int k    = b * T1 + tid;
    const int lane = tid & 63;
    const int wave = tid >> 6;

    const int   d = docs[k];
    const int   t = target[d];
    const float s = scores[d];

    // inclusive scan of s within wave
    float incl = s;
    #pragma unroll
    for (int off = 1; off < 64; off <<= 1) {
        const float v = __shfl_up(incl, off, 64);
        if (lane >= off) incl += v;
    }

    __shared__ float wsum[2];
    __shared__ float acc[11];   // [0..4]=cnt, [5..9]=Pq, [10]=unused here
    if (lane == 63) wsum[wave] = incl;
    if (tid < 11) acc[tid] = 0.0f;
    __syncthreads();

    const float excl = incl - s + (wave == 1 ? wsum[0] : 0.0f);
    atomicAdd(&acc[t], 1.0f);
    atomicAdd(&acc[5 + t], excl);
    __syncthreads();

    if (tid < 11) {
        float v = acc[tid];
        if (tid == 10) v = wsum[0] + wsum[1];   // block ssum
        ws[b * REC + tid] = v;
    }
}

// Kernel 2: one wave combines the 64 block records.
// pre_m = preoff_b + localpre_m ; suffix(m) = S_total - pre_m
// Q_v   = sum_b [ cnt_b[v]*(S_total - preoff_b) - Pq_b[v] ]
// loss  = 0.5 * sum_w c_w * ( sum_{v<w} Q_v - sum_{v>w} Q_v )
__global__ __launch_bounds__(64) void k_combine(
    const float* __restrict__ ws,
    float*       __restrict__ out)
{
    const int lane = threadIdx.x;   // 0..63 == block record index

    float cnt[5], pq[5];
    #pragma unroll
    for (int v = 0; v < 5; ++v) {
        cnt[v] = ws[lane * REC + v];
        pq[v]  = ws[lane * REC + 5 + v];
    }
    const float ssum = ws[lane * REC + 10];

    // inclusive scan of block sums -> per-block prefix offset
    float incl = ssum;
    #pragma unroll
    for (int off = 1; off < 64; off <<= 1) {
        const float v = __shfl_up(incl, off, 64);
        if (lane >= off) incl += v;
    }
    const float S_total = __shfl(incl, 63, 64);
    const float preoff  = incl - ssum;   // exclusive prefix of block sums

    double Q[5], C[5];
    #pragma unroll
    for (int v = 0; v < 5; ++v) {
        Q[v] = (double)cnt[v] * (double)(S_total - preoff) - (double)pq[v];
        C[v] = (double)cnt[v];
    }

    // reduce the 10 values across the wave
    #pragma unroll
    for (int v = 0; v < 5; ++v) {
        #pragma unroll
        for (int off = 32; off > 0; off >>= 1) {
            Q[v] += __shfl_down(Q[v], off, 64);
            C[v] += __shfl_down(C[v], off, 64);
        }
    }

    if (lane == 0) {
        double loss = 0.0;
        #pragma unroll
        for (int w = 0; w < 5; ++w) {
            double lo = 0.0, hi = 0.0;
            #pragma unroll
            for (int v = 0; v < 5; ++v) {
                if (v < w) lo += Q[v];
                if (v > w) hi += Q[v];
            }
            loss += C[w] * (lo - hi);
        }
        out[0] = (float)(0.5 * loss);
    }
}

extern "C" void kernel_launch(void* const* d_in, const int* in_sizes, int n_in,
                              void* d_out, int out_size, void* d_ws, size_t ws_size,
                              hipStream_t stream) {
    const float* scores = (const float*)d_in[0];
    const int*   target = (const int*)d_in[1];
    const int*   docs   = (const int*)d_in[2];
    float*       out    = (float*)d_out;
    float*       ws     = (float*)d_ws;

    k_gather <<<B1, T1, 0, stream>>>(scores, target, docs, ws);
    k_combine<<<1, 64, 0, stream>>>(ws, out);
}